// Round 8
// baseline (41.147 us; speedup 1.0000x reference)
//
#include <hip/hip_runtime.h>

#define NROW 128
#define NZ   8128      // 128*127/2  (divisible by 4 -> 2032 float4s)
#define EPSF 1e-12f

// One BLOCK (256 threads) per batch.
// Phase 1: cooperative contiguous float4 load of the whole z-batch into LDS
//          (fill-kernel-shaped reads: 16B/lane, 1 inst per KB).
// Phase 2: wave w computes rows [32w, 32w+32). Chunk map: lane owns
//          positions {lane, 64+lane} (LDS words consecutive per chunk ->
//          2 lanes/bank = conflict-free; stores 256B contiguous per inst).
// Closed form: 1 - s_j = prod_{k<j}(1 - z_k^2)  (telescoped scan recurrence)
//   L[i,j] = z[i,j]*sqrt(max(P_j,EPS)) (j<i), L[i,i]=sqrt(max(P_i,EPS)), 0 above.
// Per chunk: full 64-lane multiplicative DPP scan (validated R4/R7);
// chunk-1 prefix = readlane(scan0, 63) chained in via SGPR.
#define DPP_MUL(x, ctrl, rmask)                                               \
  x *= __int_as_float(__builtin_amdgcn_update_dpp(                            \
      0x3f800000, __float_as_int(x), ctrl, rmask, 0xF, false))

__global__ __launch_bounds__(256) void chol_from_z_kernel(
    const float* __restrict__ z, float* __restrict__ out)
{
    __shared__ float zs[8192];           // 8128 used + slack for dead-lane reads

    const int tid = threadIdx.x;
    const int bb  = blockIdx.x;          // batch index

    // ---- Phase 1: contiguous cooperative load (2032 float4s) ----
    {
        const float4* __restrict__ zb4 = reinterpret_cast<const float4*>(z + (size_t)bb * NZ);
        float4* __restrict__ zs4 = reinterpret_cast<float4*>(zs);
        #pragma unroll
        for (int it = 0; it < 8; ++it) {
            const int idx = it * 256 + tid;
            if (idx < NZ / 4) zs4[idx] = zb4[idx];
        }
    }
    __syncthreads();

    // ---- Phase 2: 4 waves x 32 rows ----
    const int wave = tid >> 6;
    const int lane = tid & 63;
    const int p1   = 64 + lane;          // second chunk position

    float* __restrict__ obase = out + (size_t)bb * NROW * NROW;

    #pragma unroll 4
    for (int k = 0; k < 32; ++k) {
        const int i    = (wave << 5) + k;          // row (wave-uniform)
        const int base = (i * (i - 1)) >> 1;       // scalar row offset

        // Conflict-free LDS reads (dead lanes read in-array garbage, masked below)
        const float z0 = zs[base + lane];
        const float z1 = zs[base + p1];

        const bool m0 = (lane < i);
        const bool m1 = (p1 < i);

        const float f0 = m0 ? fmaf(-z0, z0, 1.0f) : 1.0f;
        const float f1 = m1 ? fmaf(-z1, z1, 1.0f) : 1.0f;

        // Two independent 64-lane inclusive multiplicative scans (6 DPP each)
        float x0 = f0, x1 = f1;
        DPP_MUL(x0, 0x111, 0xF);  DPP_MUL(x1, 0x111, 0xF);   // row_shr:1
        DPP_MUL(x0, 0x112, 0xF);  DPP_MUL(x1, 0x112, 0xF);   // row_shr:2
        DPP_MUL(x0, 0x114, 0xF);  DPP_MUL(x1, 0x114, 0xF);   // row_shr:4
        DPP_MUL(x0, 0x118, 0xF);  DPP_MUL(x1, 0x118, 0xF);   // row_shr:8
        DPP_MUL(x0, 0x142, 0xA);  DPP_MUL(x1, 0x142, 0xA);   // row_bcast:15
        DPP_MUL(x0, 0x143, 0xC);  DPP_MUL(x1, 0x143, 0xC);   // row_bcast:31

        // Chunk-0 total -> SGPR, chains chunk 1
        const float t0 = __int_as_float(__builtin_amdgcn_readlane(__float_as_int(x0), 63));

        // Exclusive prefixes: e = inclusive / own factor (f >= 0.19 or == 1)
        const float e0 = x0 * __builtin_amdgcn_rcpf(f0);
        const float e1 = t0 * (x1 * __builtin_amdgcn_rcpf(f1));

        const float sq0 = __builtin_amdgcn_sqrtf(fmaxf(e0, EPSF));
        const float sq1 = __builtin_amdgcn_sqrtf(fmaxf(e1, EPSF));

        const float o0 = m0 ? z0 * sq0 : ((lane == i) ? sq0 : 0.0f);
        const float o1 = m1 ? z1 * sq1 : ((p1   == i) ? sq1 : 0.0f);

        // Contiguous 256B dword stores (rows are 512B-aligned)
        float* __restrict__ orow = obase + (size_t)i * NROW + lane;
        orow[0]  = o0;
        orow[64] = o1;
    }
}

extern "C" void kernel_launch(void* const* d_in, const int* in_sizes, int n_in,
                              void* d_out, int out_size, void* d_ws, size_t ws_size,
                              hipStream_t stream)
{
    const float* z = (const float*)d_in[0];
    float* out = (float*)d_out;

    const int B = in_sizes[0] / NZ;              // 2048 batches -> 2048 blocks
    chol_from_z_kernel<<<B, 256, 0, stream>>>(z, out);
}

// Round 10
// 36.204 us; speedup vs baseline: 1.1365x; 1.1365x over previous
//
#include <hip/hip_runtime.h>

#define NROW 128
#define NZ   8128      // 128*127/2
#define EPSF 1e-12f
#define RPW  8         // rows per wave (8 | 128 -> one batch per wave)

typedef float vfloat2 __attribute__((ext_vector_type(2)));  // native vec for nt-store

// R7 structure + NONTEMPORAL stores (output is write-once, never re-read:
// nt stores avoid L2/L3 allocation, keeping the 67MB z input L3-resident
// across replays and cutting read/write channel contention).
//
// One WAVE per 8 consecutive rows. Per row, lane l owns elements {2l, 2l+1}.
// Closed form: 1 - s_j = prod_{k<j}(1 - z_k^2)  (telescoped scan recurrence)
//   L[i,j] = z[i,j]*sqrt(max(P_j,EPS)) (j<i), L[i,i]=sqrt(max(P_i,EPS)), 0 above.
// Full 64-lane multiplicative scan in 6 DPP muls (validated R4/R7):
//   row_shr 1/2/4/8, row_bcast:15 -> rows{1,3}, row_bcast:31 -> rows{2,3};
//   invalid lanes return old = 1.0f = multiplicative identity.
// Loads are UNpredicated with in-batch clamped addresses (min with NZ-1):
// live lanes (p<i) are never altered (base+i-1 <= 8127); dead lanes read
// in-bounds garbage that is masked out via cndmask on f / o.
#define DPP_MUL(x, ctrl, rmask)                                               \
  x *= __int_as_float(__builtin_amdgcn_update_dpp(                            \
      0x3f800000, __float_as_int(x), ctrl, rmask, 0xF, false))

__global__ __launch_bounds__(256) void chol_from_z_kernel(
    const float* __restrict__ z, float* __restrict__ out)
{
    const int gtid = blockIdx.x * blockDim.x + threadIdx.x;
    const int w    = gtid >> 6;            // wave id
    const int lane = threadIdx.x & 63;

    const int row0 = w * RPW;              // 8 consecutive rows, same batch
    const int b    = row0 >> 7;
    const float* __restrict__ zb = z + (size_t)b * NZ;

    const int p0 = lane << 1;              // element 2l
    const int p1 = p0 | 1;                 // element 2l+1

    // ---- Phase 1: issue all 16 loads (no exec masking, addresses clamped) ----
    float zA[RPW], zB[RPW];
    #pragma unroll
    for (int k = 0; k < RPW; ++k) {
        const int i    = (row0 + k) & 127;
        const int base = (i * (i - 1)) >> 1;
        const int a0   = min(base + p0, NZ - 1);   // never alters live lanes
        const int a1   = min(base + p1, NZ - 1);
        zA[k] = zb[a0];
        zB[k] = zb[a1];
    }

    // ---- Phase 2: 8 independent scan+store streams ----
    #pragma unroll
    for (int k = 0; k < RPW; ++k) {
        const int  i  = (row0 + k) & 127;
        const bool m0 = (p0 < i);
        const bool m1 = (p1 < i);
        const float z0 = zA[k], z1 = zB[k];

        const float f0   = m0 ? fmaf(-z0, z0, 1.0f) : 1.0f;
        const float f1   = m1 ? fmaf(-z1, z1, 1.0f) : 1.0f;
        const float pair = f0 * f1;

        // Inclusive 64-lane multiplicative scan of pair (6 DPP muls)
        float x = pair;
        DPP_MUL(x, 0x111, 0xF);   // row_shr:1
        DPP_MUL(x, 0x112, 0xF);   // row_shr:2
        DPP_MUL(x, 0x114, 0xF);   // row_shr:4
        DPP_MUL(x, 0x118, 0xF);   // row_shr:8
        DPP_MUL(x, 0x142, 0xA);   // row_bcast:15 -> rows 1,3
        DPP_MUL(x, 0x143, 0xC);   // row_bcast:31 -> rows 2,3

        // Exclusive prefix: e = x / pair (pair >= 0.036 for |z|<=0.9; masked = 1)
        const float e    = x * __builtin_amdgcn_rcpf(pair);
        const float pre1 = e * f0;

        const float sq0 = __builtin_amdgcn_sqrtf(fmaxf(e,    EPSF));
        const float sq1 = __builtin_amdgcn_sqrtf(fmaxf(pre1, EPSF));

        const float o0 = m0 ? z0 * sq0 : ((p0 == i) ? sq0 : 0.0f);
        const float o1 = m1 ? z1 * sq1 : ((p1 == i) ? sq1 : 0.0f);

        // Nontemporal aligned 8B store (row base 512B-aligned, +8B*lane)
        vfloat2 v; v.x = o0; v.y = o1;
        vfloat2* dst = reinterpret_cast<vfloat2*>(out + (size_t)(row0 + k) * NROW + p0);
        __builtin_nontemporal_store(v, dst);
    }
}

extern "C" void kernel_launch(void* const* d_in, const int* in_sizes, int n_in,
                              void* d_out, int out_size, void* d_ws, size_t ws_size,
                              hipStream_t stream)
{
    const float* z = (const float*)d_in[0];
    float* out = (float*)d_out;

    const int B = in_sizes[0] / NZ;              // 2048
    const int nrows_total = B * NROW;            // 262144 rows
    const int nwaves = nrows_total / RPW;        // 32768 waves

    const int block = 256;                       // 4 waves per block
    const int grid = (nwaves * 64) / block;      // 8192 blocks, exact cover
    chol_from_z_kernel<<<grid, block, 0, stream>>>(z, out);
}

// Round 11
// 36.062 us; speedup vs baseline: 1.1410x; 1.0039x over previous
//
#include <hip/hip_runtime.h>

#define NROW 128
#define NZ   8128      // 128*127/2
#define EPSF 1e-12f
#define RPW  8         // rows per wave (8 | 128 -> one batch per wave)

typedef float vfloat2 __attribute__((ext_vector_type(2)));  // native vec for nt-store

// R10 + MERGED PAIR LOADS: lane l's elements {2l, 2l+1} are 8 contiguous
// bytes -> one global_load_dwordx2 instead of two dword loads that each
// sweep the same 9 cachelines (read line-visits/wave 144 -> ~72).
// Base clamp a = min(base+2l, NZ-2) keeps the pair in [0, NZ-1]; the clamp
// displaces only (i=127, lane63), where zA = v.y (select) and zB is dead
// (p1 = 127 = i -> diagonal path, never reads zB).
//
// One WAVE per 8 consecutive rows. Closed form (telescoped scan):
//   1 - s_j = prod_{k<j}(1 - z_k^2)
//   L[i,j] = z[i,j]*sqrt(max(P_j,EPS)) (j<i), L[i,i]=sqrt(max(P_i,EPS)), 0 above.
// Full 64-lane multiplicative scan in 6 DPP muls (validated R4/R7/R10).
// NT stores: output is write-once, never re-read (keeps z L3-resident).
#define DPP_MUL(x, ctrl, rmask)                                               \
  x *= __int_as_float(__builtin_amdgcn_update_dpp(                            \
      0x3f800000, __float_as_int(x), ctrl, rmask, 0xF, false))

__global__ __launch_bounds__(256) void chol_from_z_kernel(
    const float* __restrict__ z, float* __restrict__ out)
{
    const int gtid = blockIdx.x * blockDim.x + threadIdx.x;
    const int w    = gtid >> 6;            // wave id
    const int lane = threadIdx.x & 63;

    const int row0 = w * RPW;              // 8 consecutive rows, same batch
    const int b    = row0 >> 7;
    const float* __restrict__ zb = z + (size_t)b * NZ;

    const int p0 = lane << 1;              // element 2l
    const int p1 = p0 | 1;                 // element 2l+1

    // ---- Phase 1: 8 merged dwordx2 loads (no exec masking, base-clamped) ----
    float zA[RPW], zB[RPW];
    #pragma unroll
    for (int k = 0; k < RPW; ++k) {
        const int i    = (row0 + k) & 127;
        const int base = (i * (i - 1)) >> 1;
        const int ap   = base + p0;
        const int a    = min(ap, NZ - 2);          // shifts only (i=127, lane63)
        const float2 v = *reinterpret_cast<const float2*>(zb + a);
        zA[k] = (ap > a) ? v.y : v.x;              // shifted lane: live elem is .y
        zB[k] = v.y;                               // garbage iff shifted -> dead
    }

    // ---- Phase 2: 8 independent scan+store streams ----
    #pragma unroll
    for (int k = 0; k < RPW; ++k) {
        const int  i  = (row0 + k) & 127;
        const bool m0 = (p0 < i);
        const bool m1 = (p1 < i);
        const float z0 = zA[k], z1 = zB[k];

        const float f0   = m0 ? fmaf(-z0, z0, 1.0f) : 1.0f;
        const float f1   = m1 ? fmaf(-z1, z1, 1.0f) : 1.0f;
        const float pair = f0 * f1;

        // Inclusive 64-lane multiplicative scan of pair (6 DPP muls)
        float x = pair;
        DPP_MUL(x, 0x111, 0xF);   // row_shr:1
        DPP_MUL(x, 0x112, 0xF);   // row_shr:2
        DPP_MUL(x, 0x114, 0xF);   // row_shr:4
        DPP_MUL(x, 0x118, 0xF);   // row_shr:8
        DPP_MUL(x, 0x142, 0xA);   // row_bcast:15 -> rows 1,3
        DPP_MUL(x, 0x143, 0xC);   // row_bcast:31 -> rows 2,3

        // Exclusive prefix: e = x / pair (pair >= 0.036 for |z|<=0.9; masked = 1)
        const float e    = x * __builtin_amdgcn_rcpf(pair);
        const float pre1 = e * f0;

        const float sq0 = __builtin_amdgcn_sqrtf(fmaxf(e,    EPSF));
        const float sq1 = __builtin_amdgcn_sqrtf(fmaxf(pre1, EPSF));

        const float o0 = m0 ? z0 * sq0 : ((p0 == i) ? sq0 : 0.0f);
        const float o1 = m1 ? z1 * sq1 : ((p1 == i) ? sq1 : 0.0f);

        // Nontemporal aligned 8B store (row base 512B-aligned, +8B*lane)
        vfloat2 v; v.x = o0; v.y = o1;
        vfloat2* dst = reinterpret_cast<vfloat2*>(out + (size_t)(row0 + k) * NROW + p0);
        __builtin_nontemporal_store(v, dst);
    }
}

extern "C" void kernel_launch(void* const* d_in, const int* in_sizes, int n_in,
                              void* d_out, int out_size, void* d_ws, size_t ws_size,
                              hipStream_t stream)
{
    const float* z = (const float*)d_in[0];
    float* out = (float*)d_out;

    const int B = in_sizes[0] / NZ;              // 2048
    const int nrows_total = B * NROW;            // 262144 rows
    const int nwaves = nrows_total / RPW;        // 32768 waves

    const int block = 256;                       // 4 waves per block
    const int grid = (nwaves * 64) / block;      // 8192 blocks, exact cover
    chol_from_z_kernel<<<grid, block, 0, stream>>>(z, out);
}